// Round 1
// baseline (553.761 us; speedup 1.0000x reference)
//
#include <hip/hip_runtime.h>

#define N_NODES 50000
#define N_EDGES 800000
#define C 96
#define C3 288
#define HID 32
#define NPB 32   // nodes per block in fused MLP kernel

// ---------------- degree / normalization ----------------

__global__ void k_deg_init(float* __restrict__ deg) {
    int i = blockIdx.x * 256 + threadIdx.x;
    if (i < N_NODES) deg[i] = 1.0f;           // self-loop contributes 1
}

__global__ void k_deg(const int* __restrict__ dst, float* __restrict__ deg) {
    int e = blockIdx.x * 256 + threadIdx.x;
    if (e < N_EDGES) atomicAdd(&deg[dst[e]], 1.0f);
}

__global__ void k_dinv(const float* __restrict__ deg, float* __restrict__ dinv) {
    int i = blockIdx.x * 256 + threadIdx.x;
    if (i < N_NODES) dinv[i] = rsqrtf(deg[i]);   // deg >= 1 always
}

// ---------------- aggregation: agg = S_norm @ x  (aggregate BEFORE W_gcn) ----

// self-loop term: agg[i][c] = x[i][c] * dinv[i]^2
__global__ void k_selfloop(const float* __restrict__ x, const float* __restrict__ dinv,
                           float* __restrict__ agg) {
    long long idx = (long long)blockIdx.x * 256 + threadIdx.x;
    if (idx < (long long)N_NODES * C) {
        int i = (int)(idx / C);
        float d = dinv[i];
        agg[idx] = x[idx] * d * d;
    }
}

// one 32-lane group per edge; 3 chunks of 32 channels (96 total), coalesced
__global__ void k_scatter(const int* __restrict__ src, const int* __restrict__ dst,
                          const float* __restrict__ x, const float* __restrict__ dinv,
                          float* __restrict__ agg) {
    int g = (blockIdx.x * 256 + threadIdx.x) >> 5;   // edge id
    int l = threadIdx.x & 31;
    if (g >= N_EDGES) return;
    int s = src[g], d = dst[g];
    float norm = dinv[s] * dinv[d];
    const float* xr = x + (long long)s * C;
    float* ar = agg + (long long)d * C;
    atomicAdd(&ar[l],        xr[l]        * norm);
    atomicAdd(&ar[l + 32],   xr[l + 32]   * norm);
    atomicAdd(&ar[l + 64],   xr[l + 64]   * norm);
}

// ---------------- fused: f = agg@Wg ; hid = relu(f@W1+b1) ; out = x + hid@W2+b2

__global__ __launch_bounds__(256) void k_fused(
        const float* __restrict__ agg, const float* __restrict__ x,
        const float* __restrict__ Wg, const float* __restrict__ W1,
        const float* __restrict__ b1, const float* __restrict__ W2,
        const float* __restrict__ b2, float* __restrict__ out) {
    __shared__ float agg_s[NPB * C];     // 12 KB
    __shared__ float f_s[NPB * C3];      // 36 KB
    __shared__ float hid_s[NPB * HID];   // 4 KB
    const int t = threadIdx.x;
    const long long nbase = (long long)blockIdx.x * NPB;

    // stage agg tile (zero-pad tail so compute stays uniform)
    for (int idx = t; idx < NPB * C; idx += 256) {
        long long n = nbase + idx / C;
        agg_s[idx] = (n < N_NODES) ? agg[nbase * C + idx] : 0.0f;
    }
    __syncthreads();

    const int l = t & 31, grp = t >> 5;   // 8 groups x 32 lanes
    const int n0 = grp * 4;               // each group owns 4 nodes

    // phase B: f[NPB][288] = agg_s @ Wg.  Wg loads coalesced across lanes,
    // agg_s reads are 32-lane broadcasts (conflict-free).
    for (int jb = 0; jb < C3 / 32; ++jb) {
        int j = jb * 32 + l;
        float a0 = 0.f, a1 = 0.f, a2 = 0.f, a3 = 0.f;
        for (int k = 0; k < C; ++k) {
            float w = Wg[k * C3 + j];
            a0 += agg_s[(n0 + 0) * C + k] * w;
            a1 += agg_s[(n0 + 1) * C + k] * w;
            a2 += agg_s[(n0 + 2) * C + k] * w;
            a3 += agg_s[(n0 + 3) * C + k] * w;
        }
        f_s[(n0 + 0) * C3 + j] = a0;
        f_s[(n0 + 1) * C3 + j] = a1;
        f_s[(n0 + 2) * C3 + j] = a2;
        f_s[(n0 + 3) * C3 + j] = a3;
    }
    __syncthreads();

    // phase C: hid[NPB][32] = relu(f @ W1 + b1)
    {
        float bb = b1[l];
        for (int i = 0; i < 4; ++i) {
            int n = n0 + i;
            float acc = bb;
            for (int j = 0; j < C3; ++j)
                acc += f_s[n * C3 + j] * W1[j * HID + l];
            hid_s[n * HID + l] = fmaxf(acc, 0.0f);
        }
    }
    __syncthreads();

    // phase D: out = x + hid @ W2 + b2
    for (int idx = t; idx < NPB * C; idx += 256) {
        int n = idx / C, c = idx % C;
        long long gn = nbase + n;
        if (gn >= N_NODES) continue;
        float acc = b2[c];
        for (int h = 0; h < HID; ++h)
            acc += hid_s[n * HID + h] * W2[h * C + c];
        out[gn * C + c] = x[gn * C + c] + acc;
    }
}

// ---------------- launch ----------------

extern "C" void kernel_launch(void* const* d_in, const int* in_sizes, int n_in,
                              void* d_out, int out_size, void* d_ws, size_t ws_size,
                              hipStream_t stream) {
    const float* x   = (const float*)d_in[0];
    const float* Wg  = (const float*)d_in[1];
    const float* W1  = (const float*)d_in[2];
    const float* b1  = (const float*)d_in[3];
    const float* W2  = (const float*)d_in[4];
    const float* b2  = (const float*)d_in[5];
    // harness contract: integer inputs arrive as int32
    const int* ei  = (const int*)d_in[6];
    const int* src = ei;                 // edge_index[0]
    const int* dst = ei + N_EDGES;       // edge_index[1]
    float* out = (float*)d_out;

    float* deg  = (float*)d_ws;                    // N floats
    float* dinv = deg + N_NODES;                   // N floats
    float* agg  = dinv + N_NODES;                  // N*C floats (19.2 MB)

    k_deg_init<<<(N_NODES + 255) / 256, 256, 0, stream>>>(deg);
    k_deg<<<(N_EDGES + 255) / 256, 256, 0, stream>>>(dst, deg);
    k_dinv<<<(N_NODES + 255) / 256, 256, 0, stream>>>(deg, dinv);
    k_selfloop<<<((long long)N_NODES * C + 255) / 256, 256, 0, stream>>>(x, dinv, agg);
    k_scatter<<<((long long)N_EDGES * 32 + 255) / 256, 256, 0, stream>>>(src, dst, x, dinv, agg);
    k_fused<<<(N_NODES + NPB - 1) / NPB, 256, 0, stream>>>(agg, x, Wg, W1, b1, W2, b2, out);
}

// Round 4
// 271.909 us; speedup vs baseline: 2.0366x; 2.0366x over previous
//
#include <hip/hip_runtime.h>

#define N_NODES 50000
#define N_EDGES 800000
#define C 96
#define C3 288
#define HID 32
#define NPB 32          // nodes per block in MLP kernel
#define GPB 8           // gather: node-groups (32 lanes) per block

// ---------------- counting sort by dst: hist -> scan -> fill ----------------

__global__ void k_zero(int* __restrict__ count) {
    int i = blockIdx.x * 256 + threadIdx.x;
    if (i < N_NODES) count[i] = 0;
}

__global__ void k_hist(const int* __restrict__ dst, int* __restrict__ count) {
    int e = blockIdx.x * 256 + threadIdx.x;
    if (e < N_EDGES) atomicAdd(&count[dst[e]], 1);
}

// per-block exclusive scan over 256-element tiles
__global__ void k_scan1(const int* __restrict__ count, int* __restrict__ rowstart,
                        int* __restrict__ blocksum) {
    __shared__ int s[256];
    int t = threadIdx.x;
    int i = blockIdx.x * 256 + t;
    int v = (i < N_NODES) ? count[i] : 0;
    s[t] = v;
    __syncthreads();
    for (int off = 1; off < 256; off <<= 1) {
        int add = (t >= off) ? s[t - off] : 0;
        __syncthreads();
        s[t] += add;
        __syncthreads();
    }
    if (i < N_NODES) rowstart[i] = s[t] - v;     // exclusive within block
    if (t == 255) blocksum[blockIdx.x] = s[255];
}

__global__ void k_scan2(int* __restrict__ blocksum, int* __restrict__ blockoff, int nb) {
    __shared__ int s[256];
    int t = threadIdx.x;
    int v = (t < nb) ? blocksum[t] : 0;
    s[t] = v;
    __syncthreads();
    for (int off = 1; off < 256; off <<= 1) {
        int add = (t >= off) ? s[t - off] : 0;
        __syncthreads();
        s[t] += add;
        __syncthreads();
    }
    if (t < nb) blockoff[t] = s[t] - v;          // exclusive
}

__global__ void k_scan3(const int* __restrict__ count, int* __restrict__ rowstart,
                        const int* __restrict__ blockoff, int* __restrict__ cursor,
                        float* __restrict__ dinv) {
    int i = blockIdx.x * 256 + threadIdx.x;
    if (i < N_NODES) {
        int rs = rowstart[i] + blockoff[i >> 8];
        rowstart[i] = rs;
        cursor[i] = rs;
        dinv[i] = rsqrtf((float)(count[i] + 1));   // +1: self-loop
    }
    if (i == 0) rowstart[N_NODES] = N_EDGES;
}

__global__ void k_fill(const int* __restrict__ src, const int* __restrict__ dst,
                       int* __restrict__ cursor, int* __restrict__ srcs) {
    int e = blockIdx.x * 256 + threadIdx.x;
    if (e < N_EDGES) {
        int pos = atomicAdd(&cursor[dst[e]], 1);
        srcs[pos] = src[e];
    }
}

// ---------------- pull-gather: agg[i] = dinv_i * (sum_s dinv_s x[s] + dinv_i x[i])

__global__ __launch_bounds__(256) void k_gather(
        const int* __restrict__ rowstart, const int* __restrict__ srcs,
        const float* __restrict__ dinv, const float* __restrict__ x,
        float* __restrict__ agg) {
    int g = blockIdx.x * GPB + (threadIdx.x >> 5);   // node id
    int l = threadIdx.x & 31;
    if (g >= N_NODES) return;
    int rs = rowstart[g], re = rowstart[g + 1];
    float di = dinv[g];
    const float* xr = x + (long long)g * C;
    float a0 = di * xr[l];            // self-loop term (dinv_i * x_i)
    float a1 = di * xr[l + 32];
    float a2 = di * xr[l + 64];
    for (int e = rs; e < re; ++e) {
        int s = srcs[e];
        float ds = dinv[s];
        const float* xs = x + (long long)s * C;
        a0 += ds * xs[l];
        a1 += ds * xs[l + 32];
        a2 += ds * xs[l + 64];
    }
    float* ar = agg + (long long)g * C;
    ar[l]      = di * a0;
    ar[l + 32] = di * a1;
    ar[l + 64] = di * a2;
}

// ---------------- Wf = Wg @ W1  (96 x 32), tiny per-call GEMM ----------------

__global__ void k_wf(const float* __restrict__ Wg, const float* __restrict__ W1,
                     float* __restrict__ Wf) {
    int kt = blockIdx.x * 256 + threadIdx.x;
    if (kt >= C * HID) return;
    int k = kt >> 5, j = kt & 31;
    float acc = 0.f;
    for (int m = 0; m < C3; ++m)
        acc += Wg[k * C3 + m] * W1[m * HID + j];
    Wf[k * HID + j] = acc;
}

// ---------------- fused MLP: hid = relu(agg@Wf + b1); out = x + hid@W2 + b2 --

__global__ __launch_bounds__(256) void k_mlp(
        const float* __restrict__ agg, const float* __restrict__ x,
        const float* __restrict__ Wf, const float* __restrict__ b1,
        const float* __restrict__ W2, const float* __restrict__ b2,
        float* __restrict__ out) {
    __shared__ float agg_s[NPB * C];     // 12 KB
    __shared__ float hid_s[NPB * HID];   // 4 KB
    const int t = threadIdx.x;
    const long long nbase = (long long)blockIdx.x * NPB;

    for (int idx = t; idx < NPB * C; idx += 256) {
        long long n = nbase + idx / C;
        agg_s[idx] = (n < N_NODES) ? agg[nbase * C + idx] : 0.0f;
    }
    __syncthreads();

    const int l = t & 31, grp = t >> 5;   // 8 groups x 32 lanes
    const int n0 = grp * 4;               // each group owns 4 nodes

    // hid[n][l] = relu(sum_k agg[n][k] * Wf[k][l] + b1[l])
    {
        float bb = b1[l];
        float a0 = bb, a1 = bb, a2 = bb, a3 = bb;
        for (int k = 0; k < C; ++k) {
            float w = Wf[k * HID + l];
            a0 += agg_s[(n0 + 0) * C + k] * w;
            a1 += agg_s[(n0 + 1) * C + k] * w;
            a2 += agg_s[(n0 + 2) * C + k] * w;
            a3 += agg_s[(n0 + 3) * C + k] * w;
        }
        hid_s[(n0 + 0) * HID + l] = fmaxf(a0, 0.f);
        hid_s[(n0 + 1) * HID + l] = fmaxf(a1, 0.f);
        hid_s[(n0 + 2) * HID + l] = fmaxf(a2, 0.f);
        hid_s[(n0 + 3) * HID + l] = fmaxf(a3, 0.f);
    }
    __syncthreads();

    // out = x + hid @ W2 + b2
    for (int idx = t; idx < NPB * C; idx += 256) {
        int n = idx / C, c = idx % C;
        long long gn = nbase + n;
        if (gn >= N_NODES) continue;
        float acc = b2[c];
        for (int h = 0; h < HID; ++h)
            acc += hid_s[n * HID + h] * W2[h * C + c];
        out[gn * C + c] = x[gn * C + c] + acc;
    }
}

// ---------------- launch ----------------

extern "C" void kernel_launch(void* const* d_in, const int* in_sizes, int n_in,
                              void* d_out, int out_size, void* d_ws, size_t ws_size,
                              hipStream_t stream) {
    const float* x   = (const float*)d_in[0];
    const float* Wg  = (const float*)d_in[1];
    const float* W1  = (const float*)d_in[2];
    const float* b1  = (const float*)d_in[3];
    const float* W2  = (const float*)d_in[4];
    const float* b2  = (const float*)d_in[5];
    const int* ei  = (const int*)d_in[6];
    const int* src = ei;                 // edge_index[0]
    const int* dst = ei + N_EDGES;       // edge_index[1]
    float* out = (float*)d_out;

    // workspace layout
    char* w = (char*)d_ws;
    int*   count    = (int*)w;                 w += N_NODES * 4;
    int*   rowstart = (int*)w;                 w += (N_NODES + 1) * 4;
    int*   cursor   = (int*)w;                 w += N_NODES * 4;
    int*   blocksum = (int*)w;                 w += 256 * 4;
    int*   blockoff = (int*)w;                 w += 256 * 4;
    float* dinv     = (float*)w;               w += N_NODES * 4;
    int*   srcs     = (int*)w;                 w += N_EDGES * 4;
    float* Wf       = (float*)w;               w += C * HID * 4;
    float* agg      = (float*)w;               /* N*C floats, 19.2 MB */

    const int nb_nodes = (N_NODES + 255) / 256;   // 196
    const int nb_edges = (N_EDGES + 255) / 256;

    k_zero <<<nb_nodes, 256, 0, stream>>>(count);
    k_hist <<<nb_edges, 256, 0, stream>>>(dst, count);
    k_scan1<<<nb_nodes, 256, 0, stream>>>(count, rowstart, blocksum);
    k_scan2<<<1,        256, 0, stream>>>(blocksum, blockoff, nb_nodes);
    k_scan3<<<nb_nodes, 256, 0, stream>>>(count, rowstart, blockoff, cursor, dinv);
    k_fill <<<nb_edges, 256, 0, stream>>>(src, dst, cursor, srcs);
    k_gather<<<(N_NODES + GPB - 1) / GPB, 256, 0, stream>>>(rowstart, srcs, dinv, x, agg);
    k_wf   <<<(C * HID + 255) / 256, 256, 0, stream>>>(Wg, W1, Wf);
    k_mlp  <<<(N_NODES + NPB - 1) / NPB, 256, 0, stream>>>(agg, x, Wf, b1, W2, b2, out);
}

// Round 5
// 266.296 us; speedup vs baseline: 2.0795x; 1.0211x over previous
//
#include <hip/hip_runtime.h>

#define N_NODES 50000
#define N_EDGES 800000
#define C 96
#define C3 288
#define HID 32
#define GPB 8           // nodes (32-lane groups) per 256-thread block; 50000 = 6250*8 exactly

// ---------------- counting sort by dst: hist -> scan -> fill ----------------

__global__ void k_zero(int* __restrict__ count) {
    int i = blockIdx.x * 256 + threadIdx.x;
    if (i < N_NODES) count[i] = 0;
}

__global__ void k_hist(const int* __restrict__ dst, int* __restrict__ count) {
    int e = blockIdx.x * 256 + threadIdx.x;
    if (e < N_EDGES) atomicAdd(&count[dst[e]], 1);
}

__global__ void k_scan1(const int* __restrict__ count, int* __restrict__ rowstart,
                        int* __restrict__ blocksum) {
    __shared__ int s[256];
    int t = threadIdx.x;
    int i = blockIdx.x * 256 + t;
    int v = (i < N_NODES) ? count[i] : 0;
    s[t] = v;
    __syncthreads();
    for (int off = 1; off < 256; off <<= 1) {
        int add = (t >= off) ? s[t - off] : 0;
        __syncthreads();
        s[t] += add;
        __syncthreads();
    }
    if (i < N_NODES) rowstart[i] = s[t] - v;     // exclusive within block
    if (t == 255) blocksum[blockIdx.x] = s[255];
}

__global__ void k_scan2(int* __restrict__ blocksum, int* __restrict__ blockoff, int nb) {
    __shared__ int s[256];
    int t = threadIdx.x;
    int v = (t < nb) ? blocksum[t] : 0;
    s[t] = v;
    __syncthreads();
    for (int off = 1; off < 256; off <<= 1) {
        int add = (t >= off) ? s[t - off] : 0;
        __syncthreads();
        s[t] += add;
        __syncthreads();
    }
    if (t < nb) blockoff[t] = s[t] - v;          // exclusive
}

__global__ void k_scan3(const int* __restrict__ count, int* __restrict__ rowstart,
                        const int* __restrict__ blockoff, int* __restrict__ cursor,
                        float* __restrict__ dinv) {
    int i = blockIdx.x * 256 + threadIdx.x;
    if (i < N_NODES) {
        int rs = rowstart[i] + blockoff[i >> 8];
        rowstart[i] = rs;
        cursor[i] = rs;
        dinv[i] = rsqrtf((float)(count[i] + 1));   // +1: self-loop
    }
    if (i == 0) rowstart[N_NODES] = N_EDGES;
}

// y[i][c] = dinv[i] * x[i][c]   (float4, 1.2M elems)
__global__ void k_scale(const float* __restrict__ x, const float* __restrict__ dinv,
                        float* __restrict__ y) {
    int idx = blockIdx.x * 256 + threadIdx.x;
    if (idx < N_NODES * (C / 4)) {
        float4 v = ((const float4*)x)[idx];
        float d = dinv[idx / (C / 4)];
        v.x *= d; v.y *= d; v.z *= d; v.w *= d;
        ((float4*)y)[idx] = v;
    }
}

__global__ void k_fill(const int* __restrict__ src, const int* __restrict__ dst,
                       int* __restrict__ cursor, int* __restrict__ srcs) {
    int e = blockIdx.x * 256 + threadIdx.x;
    if (e < N_EDGES) {
        int pos = atomicAdd(&cursor[dst[e]], 1);
        srcs[pos] = src[e];
    }
}

// ---------------- Wf = Wg @ W1  (96 x 32) ----------------

__global__ void k_wf(const float* __restrict__ Wg, const float* __restrict__ W1,
                     float* __restrict__ Wf) {
    int kt = blockIdx.x * 256 + threadIdx.x;
    if (kt >= C * HID) return;
    int k = kt >> 5, j = kt & 31;
    float acc = 0.f;
    for (int m = 0; m < C3; ++m)
        acc += Wg[k * C3 + m] * W1[m * HID + j];
    Wf[k * HID + j] = acc;
}

// ---------------- fused gather + MLP + residual ----------------
// agg_row(g) = dinv[g] * ( y[g] + sum_{s in N(g)} y[s] )
// hid = relu(agg @ Wf + b1);  out = x + hid @ W2 + b2

__global__ __launch_bounds__(256) void k_fused(
        const int* __restrict__ rowstart, const int* __restrict__ srcs,
        const float* __restrict__ dinv, const float* __restrict__ y,
        const float* __restrict__ x,
        const float* __restrict__ Wf, const float* __restrict__ b1,
        const float* __restrict__ W2, const float* __restrict__ b2,
        float* __restrict__ out) {
    __shared__ float aggL[GPB][100];   // 96 padded to 100 (dodge bank aliasing)
    __shared__ float hidL[GPB][HID + 1];
    const int t = threadIdx.x, l = t & 31, grp = t >> 5;
    const int g = blockIdx.x * GPB + grp;          // always < N_NODES (exact grid)
    const int rs = rowstart[g], re = rowstart[g + 1];
    const float di = dinv[g];

    // ---- gather phase (unroll x4 for memory-level parallelism) ----
    const float* yr = y + (size_t)g * C;
    float a0 = yr[l], a1 = yr[l + 32], a2 = yr[l + 64];   // self-loop term
    int e = rs;
    for (; e + 4 <= re; e += 4) {
        int s0 = srcs[e], s1 = srcs[e + 1], s2 = srcs[e + 2], s3 = srcs[e + 3];
        const float* p0 = y + (size_t)s0 * C;
        const float* p1 = y + (size_t)s1 * C;
        const float* p2 = y + (size_t)s2 * C;
        const float* p3 = y + (size_t)s3 * C;
        float v00 = p0[l], v01 = p0[l + 32], v02 = p0[l + 64];
        float v10 = p1[l], v11 = p1[l + 32], v12 = p1[l + 64];
        float v20 = p2[l], v21 = p2[l + 32], v22 = p2[l + 64];
        float v30 = p3[l], v31 = p3[l + 32], v32 = p3[l + 64];
        a0 += (v00 + v10) + (v20 + v30);
        a1 += (v01 + v11) + (v21 + v31);
        a2 += (v02 + v12) + (v22 + v32);
    }
    for (; e < re; ++e) {
        const float* p = y + (size_t)srcs[e] * C;
        a0 += p[l]; a1 += p[l + 32]; a2 += p[l + 64];
    }
    aggL[grp][l]      = a0 * di;
    aggL[grp][l + 32] = a1 * di;
    aggL[grp][l + 64] = a2 * di;
    __syncthreads();

    // ---- hid[l] = relu(sum_k agg[k] * Wf[k][l] + b1[l]) ----
    {
        float h = b1[l];
        #pragma unroll 4
        for (int k = 0; k < C; ++k)
            h = fmaf(aggL[grp][k], Wf[k * HID + l], h);   // Wf: 12 KB, L1-resident
        hidL[grp][l] = fmaxf(h, 0.f);
    }
    __syncthreads();

    // ---- out channels l, l+32, l+64 ----
    float o0 = b2[l], o1 = b2[l + 32], o2 = b2[l + 64];
    #pragma unroll 4
    for (int hh = 0; hh < HID; ++hh) {
        float hv = hidL[grp][hh];
        o0 = fmaf(hv, W2[hh * C + l],      o0);           // W2: 12 KB, L1-resident
        o1 = fmaf(hv, W2[hh * C + l + 32], o1);
        o2 = fmaf(hv, W2[hh * C + l + 64], o2);
    }
    const float* xr = x + (size_t)g * C;
    float* orow = out + (size_t)g * C;
    orow[l]      = xr[l]      + o0;
    orow[l + 32] = xr[l + 32] + o1;
    orow[l + 64] = xr[l + 64] + o2;
}

// ---------------- launch ----------------

extern "C" void kernel_launch(void* const* d_in, const int* in_sizes, int n_in,
                              void* d_out, int out_size, void* d_ws, size_t ws_size,
                              hipStream_t stream) {
    const float* x   = (const float*)d_in[0];
    const float* Wg  = (const float*)d_in[1];
    const float* W1  = (const float*)d_in[2];
    const float* b1  = (const float*)d_in[3];
    const float* W2  = (const float*)d_in[4];
    const float* b2  = (const float*)d_in[5];
    const int* ei  = (const int*)d_in[6];
    const int* src = ei;                 // edge_index[0]
    const int* dst = ei + N_EDGES;       // edge_index[1]
    float* out = (float*)d_out;

    // workspace layout (~23.3 MB, same footprint as round-1 layout)
    char* w = (char*)d_ws;
    int*   count    = (int*)w;                 w += N_NODES * 4;
    int*   rowstart = (int*)w;                 w += (N_NODES + 1) * 4;
    int*   cursor   = (int*)w;                 w += N_NODES * 4;
    int*   blocksum = (int*)w;                 w += 256 * 4;
    int*   blockoff = (int*)w;                 w += 256 * 4;
    float* dinv     = (float*)w;               w += N_NODES * 4;
    int*   srcs     = (int*)w;                 w += N_EDGES * 4;
    float* Wf       = (float*)w;               w += C * HID * 4;
    float* y        = (float*)w;               /* N*C floats, 19.2 MB */

    const int nb_nodes = (N_NODES + 255) / 256;   // 196
    const int nb_edges = (N_EDGES + 255) / 256;

    k_zero <<<nb_nodes, 256, 0, stream>>>(count);
    k_hist <<<nb_edges, 256, 0, stream>>>(dst, count);
    k_scan1<<<nb_nodes, 256, 0, stream>>>(count, rowstart, blocksum);
    k_scan2<<<1,        256, 0, stream>>>(blocksum, blockoff, nb_nodes);
    k_scan3<<<nb_nodes, 256, 0, stream>>>(count, rowstart, blockoff, cursor, dinv);
    k_scale<<<(N_NODES * (C / 4) + 255) / 256, 256, 0, stream>>>(x, dinv, y);
    k_fill <<<nb_edges, 256, 0, stream>>>(src, dst, cursor, srcs);
    k_wf   <<<(C * HID + 255) / 256, 256, 0, stream>>>(Wg, W1, Wf);
    k_fused<<<N_NODES / GPB, 256, 0, stream>>>(rowstart, srcs, dinv, y, x,
                                               Wf, b1, W2, b2, out);
}

// Round 6
// 236.055 us; speedup vs baseline: 2.3459x; 1.1281x over previous
//
#include <hip/hip_runtime.h>

#define N_NODES 50000
#define N_EDGES 800000
#define C 96
#define C3 288
#define HID 32
#define GPB 8           // nodes (32-lane half-wave groups) per 256-thread block

// ---------------- counting sort by dst: hist -> scan -> fill ----------------

__global__ void k_zero(int* __restrict__ count) {
    int i = blockIdx.x * 256 + threadIdx.x;
    if (i < N_NODES) count[i] = 0;
}

__global__ void k_hist(const int* __restrict__ dst, int* __restrict__ count) {
    int e = blockIdx.x * 256 + threadIdx.x;
    if (e < N_EDGES) atomicAdd(&count[dst[e]], 1);
}

__global__ void k_scan1(const int* __restrict__ count, int* __restrict__ rowstart,
                        int* __restrict__ blocksum) {
    __shared__ int s[256];
    int t = threadIdx.x;
    int i = blockIdx.x * 256 + t;
    int v = (i < N_NODES) ? count[i] : 0;
    s[t] = v;
    __syncthreads();
    for (int off = 1; off < 256; off <<= 1) {
        int add = (t >= off) ? s[t - off] : 0;
        __syncthreads();
        s[t] += add;
        __syncthreads();
    }
    if (i < N_NODES) rowstart[i] = s[t] - v;     // exclusive within block
    if (t == 255) blocksum[blockIdx.x] = s[255];
}

__global__ void k_scan2(int* __restrict__ blocksum, int* __restrict__ blockoff, int nb) {
    __shared__ int s[256];
    int t = threadIdx.x;
    int v = (t < nb) ? blocksum[t] : 0;
    s[t] = v;
    __syncthreads();
    for (int off = 1; off < 256; off <<= 1) {
        int add = (t >= off) ? s[t - off] : 0;
        __syncthreads();
        s[t] += add;
        __syncthreads();
    }
    if (t < nb) blockoff[t] = s[t] - v;          // exclusive
}

__global__ void k_scan3(const int* __restrict__ count, int* __restrict__ rowstart,
                        const int* __restrict__ blockoff, int* __restrict__ cursor) {
    int i = blockIdx.x * 256 + threadIdx.x;
    if (i < N_NODES) {
        int rs = rowstart[i] + blockoff[i >> 8];
        rowstart[i] = rs;
        cursor[i] = rs;
    }
    if (i == 0) rowstart[N_NODES] = N_EDGES;
}

__global__ void k_fill(const int* __restrict__ src, const int* __restrict__ dst,
                       int* __restrict__ cursor, int* __restrict__ srcs) {
    int e = blockIdx.x * 256 + threadIdx.x;
    if (e < N_EDGES) {
        int pos = atomicAdd(&cursor[dst[e]], 1);
        srcs[pos] = src[e];
    }
}

// ---------------- Wf = Wg @ W1  (96 x 32) ----------------

__global__ void k_wf(const float* __restrict__ Wg, const float* __restrict__ W1,
                     float* __restrict__ Wf) {
    int kt = blockIdx.x * 256 + threadIdx.x;
    if (kt >= C * HID) return;
    int k = kt >> 5, j = kt & 31;
    float acc = 0.f;
    for (int m = 0; m < C3; ++m)
        acc += Wg[k * C3 + m] * W1[m * HID + j];
    Wf[k * HID + j] = acc;
}

// ---------------- z[i] = (dinv_i * x[i]) @ Wf   (N x 32, 6.4 MB) ----------------

__global__ __launch_bounds__(256) void k_z(
        const float* __restrict__ x, const int* __restrict__ count,
        const float* __restrict__ Wf, float* __restrict__ z) {
    __shared__ float xs[GPB][C];         // 3 KB; each half-wave owns its slice
    const int t = threadIdx.x, l = t & 31, grp = t >> 5;
    const int g = blockIdx.x * GPB + grp;          // exact grid: 6250*8 = 50000
    const float di = rsqrtf((float)(count[g] + 1));
    const float* xr = x + (size_t)g * C;
    // stage own row scaled by dinv (coalesced); same half-wave reads it back —
    // within-wave LDS ordering, no barrier needed
    xs[grp][l]      = xr[l]      * di;
    xs[grp][l + 32] = xr[l + 32] * di;
    xs[grp][l + 64] = xr[l + 64] * di;
    float acc = 0.f;
    #pragma unroll 8
    for (int k = 0; k < C; ++k)
        acc = fmaf(xs[grp][k], Wf[k * HID + l], acc);   // Wf: 12 KB, L1-resident
    z[(size_t)g * HID + l] = acc;
}

// ---------------- fused gather(z) + relu + W2 + residual; barrier-free ----------------

__global__ __launch_bounds__(256) void k_fused(
        const int* __restrict__ rowstart, const int* __restrict__ srcs,
        const float* __restrict__ z, const float* __restrict__ x,
        const float* __restrict__ b1, const float* __restrict__ W2,
        const float* __restrict__ b2, float* __restrict__ out) {
    const int t = threadIdx.x, l = t & 31;
    const int g = blockIdx.x * GPB + (t >> 5);     // exact grid
    const int rs = rowstart[g], re = rowstart[g + 1];
    const float di = rsqrtf((float)(re - rs + 1));

    // gather in 32-dim z-space: one coalesced 128 B row per edge
    float h = z[(size_t)g * HID + l];              // self-loop term
    int e = rs;
    for (; e + 8 <= re; e += 8) {
        int s0 = srcs[e],     s1 = srcs[e + 1], s2 = srcs[e + 2], s3 = srcs[e + 3];
        int s4 = srcs[e + 4], s5 = srcs[e + 5], s6 = srcs[e + 6], s7 = srcs[e + 7];
        float v0 = z[(size_t)s0 * HID + l], v1 = z[(size_t)s1 * HID + l];
        float v2 = z[(size_t)s2 * HID + l], v3 = z[(size_t)s3 * HID + l];
        float v4 = z[(size_t)s4 * HID + l], v5 = z[(size_t)s5 * HID + l];
        float v6 = z[(size_t)s6 * HID + l], v7 = z[(size_t)s7 * HID + l];
        h += ((v0 + v1) + (v2 + v3)) + ((v4 + v5) + (v6 + v7));
    }
    for (; e + 2 <= re; e += 2) {
        int s0 = srcs[e], s1 = srcs[e + 1];
        h += z[(size_t)s0 * HID + l] + z[(size_t)s1 * HID + l];
    }
    if (e < re) h += z[(size_t)srcs[e] * HID + l];

    const float hid = fmaxf(fmaf(h, di, b1[l]), 0.f);

    // out channels l, l+32, l+64; hid broadcast via in-wave shuffle (no LDS, no barrier)
    float o0 = b2[l], o1 = b2[l + 32], o2 = b2[l + 64];
    const int base = t & 32;                       // half-wave base lane within wave
    #pragma unroll
    for (int hh = 0; hh < HID; ++hh) {
        float hv = __shfl(hid, base + hh, 64);
        o0 = fmaf(hv, W2[hh * C + l],      o0);    // W2: 12 KB, L1-resident
        o1 = fmaf(hv, W2[hh * C + l + 32], o1);
        o2 = fmaf(hv, W2[hh * C + l + 64], o2);
    }
    const float* xr = x + (size_t)g * C;
    float* orow = out + (size_t)g * C;
    orow[l]      = xr[l]      + o0;
    orow[l + 32] = xr[l + 32] + o1;
    orow[l + 64] = xr[l + 64] + o2;
}

// ---------------- launch ----------------

extern "C" void kernel_launch(void* const* d_in, const int* in_sizes, int n_in,
                              void* d_out, int out_size, void* d_ws, size_t ws_size,
                              hipStream_t stream) {
    const float* x   = (const float*)d_in[0];
    const float* Wg  = (const float*)d_in[1];
    const float* W1  = (const float*)d_in[2];
    const float* b1  = (const float*)d_in[3];
    const float* W2  = (const float*)d_in[4];
    const float* b2  = (const float*)d_in[5];
    const int* ei  = (const int*)d_in[6];
    const int* src = ei;                 // edge_index[0]
    const int* dst = ei + N_EDGES;       // edge_index[1]
    float* out = (float*)d_out;

    // workspace layout (~10.3 MB)
    char* w = (char*)d_ws;
    int*   count    = (int*)w;                 w += N_NODES * 4;
    int*   rowstart = (int*)w;                 w += (N_NODES + 1) * 4;
    int*   cursor   = (int*)w;                 w += N_NODES * 4;
    int*   blocksum = (int*)w;                 w += 256 * 4;
    int*   blockoff = (int*)w;                 w += 256 * 4;
    int*   srcs     = (int*)w;                 w += N_EDGES * 4;
    float* Wf       = (float*)w;               w += C * HID * 4;
    float* z        = (float*)w;               /* N*HID floats, 6.4 MB */

    const int nb_nodes = (N_NODES + 255) / 256;   // 196
    const int nb_edges = (N_EDGES + 255) / 256;   // 3125

    k_zero <<<nb_nodes, 256, 0, stream>>>(count);
    k_hist <<<nb_edges, 256, 0, stream>>>(dst, count);
    k_wf   <<<(C * HID + 255) / 256, 256, 0, stream>>>(Wg, W1, Wf);
    k_scan1<<<nb_nodes, 256, 0, stream>>>(count, rowstart, blocksum);
    k_scan2<<<1,        256, 0, stream>>>(blocksum, blockoff, nb_nodes);
    k_scan3<<<nb_nodes, 256, 0, stream>>>(count, rowstart, blockoff, cursor);
    k_z    <<<N_NODES / GPB, 256, 0, stream>>>(x, count, Wf, z);
    k_fill <<<nb_edges, 256, 0, stream>>>(src, dst, cursor, srcs);
    k_fused<<<N_NODES / GPB, 256, 0, stream>>>(rowstart, srcs, z, x, b1, W2, b2, out);
}